// Round 7
// baseline (365.350 us; speedup 1.0000x reference)
//
#include <hip/hip_runtime.h>
#include <hip/hip_bf16.h>

#define NEG 0.01f
#define EPS 1e-5f

typedef __attribute__((ext_vector_type(8))) short short8;
typedef __attribute__((ext_vector_type(4))) float floatx4;

__device__ inline unsigned short f2bf(float f) {
    __hip_bfloat16 h = __float2bfloat16(f);
    union { __hip_bfloat16 h; unsigned short u; } cv; cv.h = h;
    return cv.u;
}

// ---------------------------------------------------------------- render ----
// Writes padded NHWC bf16 [64][68][68][16] INCLUDING zero borders + ch14/15.
__global__ __launch_bounds__(256) void render_kernel(const float* __restrict__ in,
                                                     unsigned short* __restrict__ out) {
    int b = blockIdx.x >> 4;
    int chunk = blockIdx.x & 15;
    __shared__ float r0[46], r1[46], r2[46], r3[46];
    __shared__ float cls_s[46 * 14];
    int tid = threadIdx.x;
    if (tid < 46) {
        const float* p = in + ((size_t)b * 46 + tid) * 18 + 14;
        float x = p[0] * 64.f, y = p[1] * 64.f, w = p[2] * 64.f, h = p[3] * 64.f;
        r0[tid] = x - 0.5f * w; r1[tid] = x + 0.5f * w;
        r2[tid] = y - 0.5f * h; r3[tid] = y + 0.5f * h;
    }
    for (int idx = tid; idx < 46 * 14; idx += 256) {
        int n = idx / 14, c = idx % 14;
        cls_s[idx] = in[((size_t)b * 46 + n) * 18 + c];
    }
    __syncthreads();
    // border zeroing: 528 border px, 33 per block
    if (tid < 33) {
        int j = chunk * 33 + tid;
        if (j < 528) {
            int y, x;
            if (j < 136) { y = j / 68; x = j - y * 68; }
            else if (j < 272) { int t = j - 136; int yy = t / 68; y = 66 + yy; x = t - yy * 68; }
            else { int t = j - 272; y = 2 + (t >> 2); int k = t & 3; x = (k < 2) ? k : 64 + k; }
            size_t zb = (((size_t)b * 68 + y) * 68 + x) * 16;
            short8 z;
#pragma unroll
            for (int i = 0; i < 8; ++i) z[i] = 0;
            *(short8*)(out + zb) = z;
            *(short8*)(out + zb + 8) = z;
        }
    }
    int pix = chunk * 256 + tid;
    float cx = (float)(pix & 63);
    float cy = (float)(pix >> 6);
    float acc[14];
#pragma unroll
    for (int c = 0; c < 14; ++c) acc[c] = 0.f;
    for (int n = 0; n < 46; ++n) {
        float x0 = r0[n], x1 = r1[n], y0 = r2[n], y1 = r3[n];
        float by = fminf(fmaxf(cy - y0, 0.f), 1.f) * fminf(fmaxf(y1 - cy, 0.f), 1.f);
        float bx = fminf(fmaxf(cx - x0, 0.f), 1.f) * fminf(fmaxf(x1 - cx, 0.f), 1.f);
        float kx0 = fmaxf(1.f - fabsf(cx - x0), 0.f);
        float kx1 = fmaxf(1.f - fabsf(cx - x1), 0.f);
        float ky0 = fmaxf(1.f - fabsf(cy - y0), 0.f);
        float ky1 = fmaxf(1.f - fabsf(cy - y1), 0.f);
        float r = fmaxf(fmaxf(kx0 * by, kx1 * by), fmaxf(ky0 * bx, ky1 * bx));
        if (r > 0.f) {
#pragma unroll
            for (int c = 0; c < 14; ++c) acc[c] = fmaf(cls_s[n * 14 + c], r, acc[c]);
        }
    }
    size_t obase = (((size_t)b * 68 + ((pix >> 6) + 2)) * 68 + ((pix & 63) + 2)) * 16;
    short8 v0, v1;
#pragma unroll
    for (int i = 0; i < 8; ++i) v0[i] = (short)f2bf(acc[i]);
#pragma unroll
    for (int i = 0; i < 6; ++i) v1[i] = (short)f2bf(acc[8 + i]);
    v1[6] = 0; v1[7] = 0;
    *(short8*)(out + obase) = v0;
    *(short8*)(out + obase + 8) = v1;
}

// ------------------------------------------- merged weight transform --------
__global__ __launch_bounds__(256) void wtrans_all(const float* __restrict__ w1,
                                                  const float* __restrict__ w2,
                                                  const float* __restrict__ w3,
                                                  unsigned short* __restrict__ wT1,
                                                  unsigned short* __restrict__ wT2,
                                                  unsigned short* __restrict__ wT3) {
    int idx = blockIdx.x * 256 + threadIdx.x;
    const float* w; unsigned short* wT; int CIN, CPLOG, SUB, COLOG;
    if (idx < 30720) { w = w1; wT = wT1; CIN = 14; CPLOG = 4; SUB = 3; COLOG = 6; }
    else if (idx < 235520) { idx -= 30720; w = w2; wT = wT2; CIN = 64; CPLOG = 6; SUB = 10; COLOG = 7; }
    else if (idx < 1054720) { idx -= 235520; w = w3; wT = wT3; CIN = 128; CPLOG = 7; SUB = 20; COLOG = 8; }
    else return;
    int kk = idx & 31;
    int co = (idx >> 5) & ((1 << COLOG) - 1);
    int s = idx >> (5 + COLOG);
    int kh = s / SUB, sub = s - kh * SUB;
    int kidx = sub * 32 + kk;
    int kw = kidx >> CPLOG;
    int ci = kidx & ((1 << CPLOG) - 1);
    float v = (kw < 5 && ci < CIN) ? w[((size_t)(co * CIN + ci) * 5 + kh) * 5 + kw] : 0.f;
    wT[idx] = f2bf(v);
}

// ------------------------------ streaming implicit-GEMM MFMA conv -----------
// NO LDS staging, NO K-loop barriers. A and B fragments loaded directly from
// global in MFMA-ready layout (both 1KB-coalesced per wave per fragment);
// B-reuse via L1/L2 (wT <= 1.6 MB). Fully unrolled K-loop -> deep load ILP.
// Fused BN stats: wave shfl-reduce (+1 end barrier if NW>1) -> atomics.
template <int CP, int COUT, int HP, int LOG_OHW, int LOG_OW, int SUB,
          int NCO, int NT, int NW>
__global__ __launch_bounds__(NW * 64) void conv_stream(
        const unsigned short* __restrict__ inP,
        const unsigned short* __restrict__ wT,
        float* __restrict__ outX,
        float* __restrict__ stacc) {
    constexpr int COT = NT * 16;
    __shared__ float sred[NW][2][COT];
    int tid = threadIdx.x;
    int wave = tid >> 6, lane = tid & 63, q = lane >> 4, l16 = lane & 15;
    int bm = blockIdx.x / NCO, bco = blockIdx.x % NCO;

    const short* aB[4];
#pragma unroll
    for (int f = 0; f < 4; ++f) {
        int m = bm * (NW * 64) + wave * 64 + f * 16 + l16;
        int b = m >> LOG_OHW;
        int ohw = m & ((1 << LOG_OHW) - 1);
        int oh = ohw >> LOG_OW, ow = ohw & ((1 << LOG_OW) - 1);
        aB[f] = (const short*)inP + ((size_t)((b * HP + 2 * oh) * HP + 2 * ow)) * CP + q * 8;
    }
    const short* bB = (const short*)wT + (size_t)(bco * COT + l16) * 32 + q * 8;

    floatx4 acc[4][NT];
#pragma unroll
    for (int f = 0; f < 4; ++f)
#pragma unroll
        for (int nt = 0; nt < NT; ++nt) acc[f][nt] = (floatx4){0.f, 0.f, 0.f, 0.f};

#pragma unroll
    for (int kh = 0; kh < 5; ++kh) {
#pragma unroll
        for (int sub = 0; sub < SUB; ++sub) {
            int step = kh * SUB + sub;
            short8 af[4];
#pragma unroll
            for (int f = 0; f < 4; ++f)
                af[f] = *(const short8*)(aB[f] + (size_t)(kh * HP) * CP + sub * 32);
            short8 bf[NT];
#pragma unroll
            for (int nt = 0; nt < NT; ++nt)
                bf[nt] = *(const short8*)(bB + (size_t)step * COUT * 32 + nt * 512);
#pragma unroll
            for (int nt = 0; nt < NT; ++nt)
#pragma unroll
                for (int f = 0; f < 4; ++f)
                    acc[f][nt] = __builtin_amdgcn_mfma_f32_16x16x32_bf16(af[f], bf[nt], acc[f][nt], 0, 0, 0);
        }
    }
    // output
#pragma unroll
    for (int f = 0; f < 4; ++f)
#pragma unroll
        for (int nt = 0; nt < NT; ++nt)
#pragma unroll
            for (int rg = 0; rg < 4; ++rg) {
                int mg = bm * (NW * 64) + wave * 64 + f * 16 + q * 4 + rg;
                int co = bco * COT + nt * 16 + l16;
                outX[(size_t)mg * COUT + co] = acc[f][nt][rg];
            }
    // fused BN stats
    float ps[NT], ps2[NT];
#pragma unroll
    for (int nt = 0; nt < NT; ++nt) {
        float s = 0.f, s2 = 0.f;
#pragma unroll
        for (int f = 0; f < 4; ++f)
#pragma unroll
            for (int rg = 0; rg < 4; ++rg) {
                float v = acc[f][nt][rg];
                s += v; s2 = fmaf(v, v, s2);
            }
        s += __shfl_xor(s, 16); s += __shfl_xor(s, 32);
        s2 += __shfl_xor(s2, 16); s2 += __shfl_xor(s2, 32);
        ps[nt] = s; ps2[nt] = s2;
    }
    if (NW == 1) {
        if (q == 0) {
#pragma unroll
            for (int nt = 0; nt < NT; ++nt) {
                int co = bco * COT + nt * 16 + l16;
                atomicAdd(&stacc[co], ps[nt]);
                atomicAdd(&stacc[COUT + co], ps2[nt]);
            }
        }
    } else {
        if (q == 0) {
#pragma unroll
            for (int nt = 0; nt < NT; ++nt) {
                sred[wave][0][nt * 16 + l16] = ps[nt];
                sred[wave][1][nt * 16 + l16] = ps2[nt];
            }
        }
        __syncthreads();
        if (tid < COT) {
            float ts = 0.f, ts2 = 0.f;
#pragma unroll
            for (int w = 0; w < NW; ++w) { ts += sred[w][0][tid]; ts2 += sred[w][1][tid]; }
            atomicAdd(&stacc[bco * COT + tid], ts);
            atomicAdd(&stacc[COUT + bco * COT + tid], ts2);
        }
    }
}

// ------------------------------ conv4: streaming split-K GEMM ---------------
// Wave tile 64m x 64co; grid = 16 co-groups x 16 k-splits (B read exactly
// once, 64 MB HBM floor). B fp32 -> bf16 inline. Single-wave blocks, no LDS.
__global__ __launch_bounds__(64) void conv4_stream(const unsigned short* __restrict__ A,
                                                   const float* __restrict__ w4,
                                                   float* __restrict__ h4) {
    int lane = threadIdx.x, q = lane >> 4, l16 = lane & 15;
    int bco = blockIdx.x & 15;
    int ks = blockIdx.x >> 4;
    const short* aB[4];
#pragma unroll
    for (int f = 0; f < 4; ++f)
        aB[f] = (const short*)A + (size_t)(f * 16 + l16) * 16384 + ks * 1024 + q * 8;
    const float* bB = w4 + (size_t)(bco * 64 + l16) * 16384 + ks * 1024 + q * 8;

    floatx4 acc[4][4];
#pragma unroll
    for (int f = 0; f < 4; ++f)
#pragma unroll
        for (int nt = 0; nt < 4; ++nt) acc[f][nt] = (floatx4){0.f, 0.f, 0.f, 0.f};

#pragma unroll 8
    for (int step = 0; step < 32; ++step) {
        short8 af[4];
#pragma unroll
        for (int f = 0; f < 4; ++f)
            af[f] = *(const short8*)(aB[f] + step * 32);
        short8 bf[4];
#pragma unroll
        for (int nt = 0; nt < 4; ++nt) {
            const float* p = bB + (size_t)nt * 16 * 16384 + step * 32;
            float4 b0 = *(const float4*)p;
            float4 b1 = *(const float4*)(p + 4);
            bf[nt][0] = (short)f2bf(b0.x); bf[nt][1] = (short)f2bf(b0.y);
            bf[nt][2] = (short)f2bf(b0.z); bf[nt][3] = (short)f2bf(b0.w);
            bf[nt][4] = (short)f2bf(b1.x); bf[nt][5] = (short)f2bf(b1.y);
            bf[nt][6] = (short)f2bf(b1.z); bf[nt][7] = (short)f2bf(b1.w);
        }
#pragma unroll
        for (int nt = 0; nt < 4; ++nt)
#pragma unroll
            for (int f = 0; f < 4; ++f)
                acc[f][nt] = __builtin_amdgcn_mfma_f32_16x16x32_bf16(af[f], bf[nt], acc[f][nt], 0, 0, 0);
    }
#pragma unroll
    for (int f = 0; f < 4; ++f)
#pragma unroll
        for (int nt = 0; nt < 4; ++nt)
#pragma unroll
            for (int rg = 0; rg < 4; ++rg) {
                int mg = f * 16 + q * 4 + rg;
                int co = bco * 64 + nt * 16 + l16;
                atomicAdd(&h4[(size_t)mg * 1024 + co], acc[f][nt][rg]);
            }
}

// ----------------------------------------------------------- batch stats ----
__global__ __launch_bounds__(256) void stats_part(const float* __restrict__ X,
                                                  float* __restrict__ acc,
                                                  int CO, int R, int RPB, int CGLOG) {
    int tid = threadIdx.x;
    int cg = blockIdx.x & ((1 << CGLOG) - 1);
    int rb = blockIdx.x >> CGLOG;
    int c = (cg << 6) + (tid & 63);
    int w = tid >> 6;
    float s = 0.f, s2 = 0.f;
    int rend = min(R, (rb + 1) * RPB);
    for (int r = rb * RPB + w; r < rend; r += 4) {
        float v = X[(size_t)r * CO + c];
        s += v; s2 += v * v;
    }
    __shared__ float ls[4][64], ls2[4][64];
    ls[w][tid & 63] = s; ls2[w][tid & 63] = s2;
    __syncthreads();
    if (tid < 64) {
        float ts = ls[0][tid] + ls[1][tid] + ls[2][tid] + ls[3][tid];
        float ts2 = ls2[0][tid] + ls2[1][tid] + ls2[2][tid] + ls2[3][tid];
        int cc = (cg << 6) + tid;
        atomicAdd(&acc[cc], ts);
        atomicAdd(&acc[CO + cc], ts2);
    }
}

// ------------------- BN(inline finalize) + lrelu + pad + bf16 (NHWC) --------
__global__ __launch_bounds__(256) void bnpad_kernel(const float* __restrict__ X,
                                                    const float* __restrict__ stacc,
                                                    const float* __restrict__ g,
                                                    const float* __restrict__ bb,
                                                    unsigned short* __restrict__ out,
                                                    int CO_LOG, int OH, int OHP,
                                                    float invN, int total) {
    int idx = blockIdx.x * 256 + threadIdx.x;
    if (idx >= total) return;
    int CO = 1 << CO_LOG;
    int c = idx & (CO - 1);
    float mean = stacc[c] * invN;
    float var = fmaxf(stacc[CO + c] * invN - mean * mean, 0.f);
    float sc = g[c] * rsqrtf(var + EPS);
    float sh = bb[c] - mean * sc;
    int t = idx >> CO_LOG;
    int x = t % OHP; t /= OHP;
    int y = t % OHP; int b = t / OHP;
    unsigned short v = 0;
    if (y >= 2 && y < OH + 2 && x >= 2 && x < OH + 2) {
        float f = X[(((size_t)(b * OH + (y - 2)) * OH + (x - 2)) << CO_LOG) + c];
        f = f * sc + sh;
        f = f >= 0.f ? f : NEG * f;
        v = f2bf(f);
    }
    out[idx] = v;
}

// -------- BN(inline finalize) + lrelu + bf16, NHWC -> NCHW (conv4 input) ----
__global__ __launch_bounds__(256) void bn_nchw_kernel(const float* __restrict__ X,
                                                      const float* __restrict__ stacc,
                                                      const float* __restrict__ g,
                                                      const float* __restrict__ bb,
                                                      unsigned short* __restrict__ out,
                                                      int total) {
    int idx = blockIdx.x * 256 + threadIdx.x;
    if (idx >= total) return;
    int hw = idx & 63;
    int ci = (idx >> 6) & 255;
    int b = idx >> 14;
    float mean = stacc[ci] * (1.f / 4096.f);
    float var = fmaxf(stacc[256 + ci] * (1.f / 4096.f) - mean * mean, 0.f);
    float sc = g[ci] * rsqrtf(var + EPS);
    float sh = bb[ci] - mean * sc;
    float f = X[((size_t)(b * 64 + hw)) * 256 + ci] * sc + sh;
    f = f >= 0.f ? f : NEG * f;
    out[idx] = f2bf(f);
}

// -------------------------------------- conv5 (inline BN4 finalize) ---------
__global__ __launch_bounds__(256) void conv5_kernel(const float* __restrict__ X,
                                                    const float* __restrict__ stacc,
                                                    const float* __restrict__ g,
                                                    const float* __restrict__ bb,
                                                    const float* __restrict__ w5,
                                                    const float* __restrict__ b5,
                                                    float* __restrict__ out) {
    int b = blockIdx.x, tid = threadIdx.x;
    float s = 0.f;
    for (int c = tid; c < 1024; c += 256) {
        float mean = stacc[c] * (1.f / 64.f);
        float var = fmaxf(stacc[1024 + c] * (1.f / 64.f) - mean * mean, 0.f);
        float sc = g[c] * rsqrtf(var + EPS);
        float sh = bb[c] - mean * sc;
        float f = X[(size_t)b * 1024 + c] * sc + sh;
        f = f >= 0.f ? f : NEG * f;
        s = fmaf(f, w5[c], s);
    }
#pragma unroll
    for (int off = 32; off > 0; off >>= 1) s += __shfl_down(s, off);
    __shared__ float ls[4];
    if ((tid & 63) == 0) ls[tid >> 6] = s;
    __syncthreads();
    if (tid == 0) out[b] = ls[0] + ls[1] + ls[2] + ls[3] + b5[0];
}

// ----------------------------------------------------------------- launch ---
extern "C" void kernel_launch(void* const* d_in, const int* in_sizes, int n_in,
                              void* d_out, int out_size, void* d_ws, size_t ws_size,
                              hipStream_t stream) {
    (void)in_sizes; (void)n_in; (void)out_size; (void)ws_size;
    const float* input_data = (const float*)d_in[0];
    const float* w1 = (const float*)d_in[2];
    const float* g1 = (const float*)d_in[3];
    const float* b1 = (const float*)d_in[4];
    const float* w2 = (const float*)d_in[5];
    const float* g2 = (const float*)d_in[6];
    const float* b2 = (const float*)d_in[7];
    const float* w3 = (const float*)d_in[8];
    const float* g3 = (const float*)d_in[9];
    const float* b3 = (const float*)d_in[10];
    const float* w4 = (const float*)d_in[11];
    const float* g4 = (const float*)d_in[12];
    const float* b4 = (const float*)d_in[13];
    const float* w5 = (const float*)d_in[14];
    const float* b5 = (const float*)d_in[15];

    char* ws = (char*)d_ws;
    float* regA = (float*)ws;               // 16.8 MB: conv1out / conv3out
    char* wsB = ws + 16777216;              // 10.7 MB: pad1 / pad2
    char* wsC = wsB + 10616832;             // 9.5 MB: rendered / conv2out / a4
    char* wsD = wsC + 9469952;
    float* h4  = (float*)wsD;                               // 262,144 B
    float* st1 = (float*)(wsD + 262144);                    // 512 B  (64*2)
    float* st2 = (float*)(wsD + 262656);                    // 1024 B (128*2)
    float* st3 = (float*)(wsD + 263680);                    // 2048 B (256*2)
    float* st4 = (float*)(wsD + 265728);                    // 8192 B (1024*2)
    unsigned short* wT1 = (unsigned short*)(wsD + 274432);  // 61,440 B
    unsigned short* wT2 = (unsigned short*)(wsD + 335872);  // 409,600 B
    unsigned short* wT3 = (unsigned short*)(wsD + 745472);  // 1,638,400 B

    unsigned short* rendered = (unsigned short*)wsC;
    float* conv1out = regA;
    unsigned short* pad1 = (unsigned short*)wsB;
    float* conv2out = (float*)wsC;
    unsigned short* pad2 = (unsigned short*)wsB;
    float* conv3out = regA;
    unsigned short* a4 = (unsigned short*)wsC;

    // one memset covers h4 + all stat accumulators
    hipMemsetAsync(wsD, 0, 273920, stream);
    wtrans_all<<<4120, 256, 0, stream>>>(w1, w2, w3, wT1, wT2, wT3);
    render_kernel<<<1024, 256, 0, stream>>>(input_data, rendered);

    // conv1: [65536,480]x[480,64] — 256 blocks x 4 waves, NT=4
    conv_stream<16, 64, 68, 10, 5, 3, 1, 4, 4><<<256, 256, 0, stream>>>(rendered, wT1, conv1out, st1);
    bnpad_kernel<<<20736, 256, 0, stream>>>(conv1out, st1, g1, b1, pad1, 6, 32, 36, 1.f / 65536.f, 5308416);

    // conv2: [16384,1600]x[1600,128] — 128m x 2co = 256 blocks x 2 waves, NT=4
    conv_stream<64, 128, 36, 8, 4, 10, 2, 4, 2><<<256, 128, 0, stream>>>(pad1, wT2, conv2out, st2);
    bnpad_kernel<<<12800, 256, 0, stream>>>(conv2out, st2, g2, b2, pad2, 7, 16, 20, 1.f / 16384.f, 3276800);

    // conv3: [4096,3200]x[3200,256] — 64m x 4co = 256 single-wave blocks, NT=4
    conv_stream<128, 256, 20, 6, 3, 20, 4, 4, 1><<<256, 64, 0, stream>>>(pad2, wT3, conv3out, st3);
    bn_nchw_kernel<<<4096, 256, 0, stream>>>(conv3out, st3, g3, b3, a4, 1048576);

    // conv4: [64,16384] x [1024,16384]^T -> [64,1024], 16co x 16ks single-wave blocks
    conv4_stream<<<256, 64, 0, stream>>>(a4, w4, h4);
    stats_part<<<16, 256, 0, stream>>>(h4, st4, 1024, 64, 64, 4);

    // conv5 (inline BN4)
    conv5_kernel<<<64, 256, 0, stream>>>(h4, st4, g4, b4, w5, b5, (float*)d_out);
}

// Round 8
// 318.550 us; speedup vs baseline: 1.1469x; 1.1469x over previous
//
#include <hip/hip_runtime.h>
#include <hip/hip_bf16.h>

#define NEG 0.01f
#define EPS 1e-5f

typedef __attribute__((ext_vector_type(8))) short short8;
typedef __attribute__((ext_vector_type(4))) float floatx4;

__device__ inline unsigned short f2bf(float f) {
    __hip_bfloat16 h = __float2bfloat16(f);
    union { __hip_bfloat16 h; unsigned short u; } cv; cv.h = h;
    return cv.u;
}

// ---------------------------------------------------------------- render ----
// Writes padded NHWC bf16 [64][68][68][16] INCLUDING zero borders + ch14/15.
__global__ __launch_bounds__(256) void render_kernel(const float* __restrict__ in,
                                                     unsigned short* __restrict__ out) {
    int b = blockIdx.x >> 4;
    int chunk = blockIdx.x & 15;
    __shared__ float r0[46], r1[46], r2[46], r3[46];
    __shared__ float cls_s[46 * 14];
    int tid = threadIdx.x;
    if (tid < 46) {
        const float* p = in + ((size_t)b * 46 + tid) * 18 + 14;
        float x = p[0] * 64.f, y = p[1] * 64.f, w = p[2] * 64.f, h = p[3] * 64.f;
        r0[tid] = x - 0.5f * w; r1[tid] = x + 0.5f * w;
        r2[tid] = y - 0.5f * h; r3[tid] = y + 0.5f * h;
    }
    for (int idx = tid; idx < 46 * 14; idx += 256) {
        int n = idx / 14, c = idx % 14;
        cls_s[idx] = in[((size_t)b * 46 + n) * 18 + c];
    }
    __syncthreads();
    if (tid < 33) {
        int j = chunk * 33 + tid;
        if (j < 528) {
            int y, x;
            if (j < 136) { y = j / 68; x = j - y * 68; }
            else if (j < 272) { int t = j - 136; int yy = t / 68; y = 66 + yy; x = t - yy * 68; }
            else { int t = j - 272; y = 2 + (t >> 2); int k = t & 3; x = (k < 2) ? k : 64 + k; }
            size_t zb = (((size_t)b * 68 + y) * 68 + x) * 16;
            short8 z;
#pragma unroll
            for (int i = 0; i < 8; ++i) z[i] = 0;
            *(short8*)(out + zb) = z;
            *(short8*)(out + zb + 8) = z;
        }
    }
    int pix = chunk * 256 + tid;
    float cx = (float)(pix & 63);
    float cy = (float)(pix >> 6);
    float acc[14];
#pragma unroll
    for (int c = 0; c < 14; ++c) acc[c] = 0.f;
    for (int n = 0; n < 46; ++n) {
        float x0 = r0[n], x1 = r1[n], y0 = r2[n], y1 = r3[n];
        float by = fminf(fmaxf(cy - y0, 0.f), 1.f) * fminf(fmaxf(y1 - cy, 0.f), 1.f);
        float bx = fminf(fmaxf(cx - x0, 0.f), 1.f) * fminf(fmaxf(x1 - cx, 0.f), 1.f);
        float kx0 = fmaxf(1.f - fabsf(cx - x0), 0.f);
        float kx1 = fmaxf(1.f - fabsf(cx - x1), 0.f);
        float ky0 = fmaxf(1.f - fabsf(cy - y0), 0.f);
        float ky1 = fmaxf(1.f - fabsf(cy - y1), 0.f);
        float r = fmaxf(fmaxf(kx0 * by, kx1 * by), fmaxf(ky0 * bx, ky1 * bx));
        if (r > 0.f) {
#pragma unroll
            for (int c = 0; c < 14; ++c) acc[c] = fmaf(cls_s[n * 14 + c], r, acc[c]);
        }
    }
    size_t obase = (((size_t)b * 68 + ((pix >> 6) + 2)) * 68 + ((pix & 63) + 2)) * 16;
    short8 v0, v1;
#pragma unroll
    for (int i = 0; i < 8; ++i) v0[i] = (short)f2bf(acc[i]);
#pragma unroll
    for (int i = 0; i < 6; ++i) v1[i] = (short)f2bf(acc[8 + i]);
    v1[6] = 0; v1[7] = 0;
    *(short8*)(out + obase) = v0;
    *(short8*)(out + obase + 8) = v1;
}

// ------------------------------------------- merged weight transform --------
__global__ __launch_bounds__(256) void wtrans_all(const float* __restrict__ w1,
                                                  const float* __restrict__ w2,
                                                  const float* __restrict__ w3,
                                                  unsigned short* __restrict__ wT1,
                                                  unsigned short* __restrict__ wT2,
                                                  unsigned short* __restrict__ wT3) {
    int idx = blockIdx.x * 256 + threadIdx.x;
    const float* w; unsigned short* wT; int CIN, CPLOG, SUB, COLOG;
    if (idx < 30720) { w = w1; wT = wT1; CIN = 14; CPLOG = 4; SUB = 3; COLOG = 6; }
    else if (idx < 235520) { idx -= 30720; w = w2; wT = wT2; CIN = 64; CPLOG = 6; SUB = 10; COLOG = 7; }
    else if (idx < 1054720) { idx -= 235520; w = w3; wT = wT3; CIN = 128; CPLOG = 7; SUB = 20; COLOG = 8; }
    else return;
    int kk = idx & 31;
    int co = (idx >> 5) & ((1 << COLOG) - 1);
    int s = idx >> (5 + COLOG);
    int kh = s / SUB, sub = s - kh * SUB;
    int kidx = sub * 32 + kk;
    int kw = kidx >> CPLOG;
    int ci = kidx & ((1 << CPLOG) - 1);
    float v = (kw < 5 && ci < CIN) ? w[((size_t)(co * CIN + ci) * 5 + kh) * 5 + kw] : 0.f;
    wT[idx] = f2bf(v);
}

// ------------------------------------- conv1: MFMA conv + fused BN stats ----
// R5-proven structure: NW waves, direct-global A, LDS double-buffered B,
// one barrier per CH-step chunk, fused BN stats.
template <int CP, int COUT, int HP, int LOG_OHW, int LOG_OW, int SUB,
          int NCO, int NT, int CH, int NW>
__global__ __launch_bounds__(NW * 64) void conv_mfma(
        const unsigned short* __restrict__ inP,
        const unsigned short* __restrict__ wT,
        float* __restrict__ outX,
        float* __restrict__ stacc) {
    constexpr int NSTEP = 5 * SUB;
    constexpr int NCHUNK = NSTEP / CH;
    constexpr int COT = NT * 16;
    constexpr int NSTG = (CH * COT * 4) / (NW * 64);
    __shared__ short Bs[2][CH][COT][32];
    __shared__ float sred[NW][2][COT];
    int tid = threadIdx.x;
    int wave = tid >> 6, lane = tid & 63, q = lane >> 4, l16 = lane & 15;
    int bm = blockIdx.x / NCO, bco = blockIdx.x % NCO;

    const short* aB[4];
#pragma unroll
    for (int f = 0; f < 4; ++f) {
        int m = bm * (NW * 64) + wave * 64 + f * 16 + l16;
        int b = m >> LOG_OHW;
        int ohw = m & ((1 << LOG_OHW) - 1);
        int oh = ohw >> LOG_OW, ow = ohw & ((1 << LOG_OW) - 1);
        aB[f] = (const short*)inP + ((size_t)((b * HP + 2 * oh) * HP + 2 * ow)) * CP + q * 8;
    }
    const short* bgbase = (const short*)wT + (size_t)bco * COT * 32;

    floatx4 acc[4][NT];
#pragma unroll
    for (int f = 0; f < 4; ++f)
#pragma unroll
        for (int nt = 0; nt < NT; ++nt) acc[f][nt] = (floatx4){0.f, 0.f, 0.f, 0.f};

    short8 nb[NSTG];
#pragma unroll
    for (int i = 0; i < NSTG; ++i) {
        int v = tid + i * NW * 64;
        int s = v / (COT * 4);
        int rem = v - s * (COT * 4);
        nb[i] = *(const short8*)(bgbase + ((size_t)s * COUT) * 32 + rem * 8);
    }
#pragma unroll
    for (int i = 0; i < NSTG; ++i) {
        int v = tid + i * NW * 64;
        int s = v / (COT * 4);
        int rem = v - s * (COT * 4);
        *(short8*)((short*)&Bs[0][s][0][0] + rem * 8) = nb[i];
    }
    __syncthreads();

    for (int chunk = 0; chunk < NCHUNK; ++chunk) {
        int cur = chunk & 1;
        if (chunk + 1 < NCHUNK) {
            int step0 = (chunk + 1) * CH;
#pragma unroll
            for (int i = 0; i < NSTG; ++i) {
                int v = tid + i * NW * 64;
                int s = v / (COT * 4);
                int rem = v - s * (COT * 4);
                nb[i] = *(const short8*)(bgbase + ((size_t)(step0 + s) * COUT) * 32 + rem * 8);
            }
        }
#pragma unroll
        for (int s = 0; s < CH; ++s) {
            int step = chunk * CH + s;
            int kh = step / SUB, sub = step - kh * SUB;
            short8 af[4];
#pragma unroll
            for (int f = 0; f < 4; ++f)
                af[f] = *(const short8*)(aB[f] + (size_t)(kh * HP) * CP + sub * 32);
#pragma unroll
            for (int nt = 0; nt < NT; ++nt) {
                short8 bf = *(const short8*)&Bs[cur][s][nt * 16 + l16][q * 8];
#pragma unroll
                for (int f = 0; f < 4; ++f)
                    acc[f][nt] = __builtin_amdgcn_mfma_f32_16x16x32_bf16(af[f], bf, acc[f][nt], 0, 0, 0);
            }
        }
        if (chunk + 1 < NCHUNK) {
#pragma unroll
            for (int i = 0; i < NSTG; ++i) {
                int v = tid + i * NW * 64;
                int s = v / (COT * 4);
                int rem = v - s * (COT * 4);
                *(short8*)((short*)&Bs[cur ^ 1][s][0][0] + rem * 8) = nb[i];
            }
            __syncthreads();
        }
    }
#pragma unroll
    for (int f = 0; f < 4; ++f)
#pragma unroll
        for (int nt = 0; nt < NT; ++nt)
#pragma unroll
            for (int rg = 0; rg < 4; ++rg) {
                int mg = bm * (NW * 64) + wave * 64 + f * 16 + q * 4 + rg;
                int co = bco * COT + nt * 16 + l16;
                outX[(size_t)mg * COUT + co] = acc[f][nt][rg];
            }
#pragma unroll
    for (int nt = 0; nt < NT; ++nt) {
        float s = 0.f, s2 = 0.f;
#pragma unroll
        for (int f = 0; f < 4; ++f)
#pragma unroll
            for (int rg = 0; rg < 4; ++rg) {
                float v = acc[f][nt][rg];
                s += v; s2 = fmaf(v, v, s2);
            }
        s += __shfl_xor(s, 16); s += __shfl_xor(s, 32);
        s2 += __shfl_xor(s2, 16); s2 += __shfl_xor(s2, 32);
        if (q == 0) {
            sred[wave][0][nt * 16 + l16] = s;
            sred[wave][1][nt * 16 + l16] = s2;
        }
    }
    __syncthreads();
    if (tid < COT) {
        float ts = 0.f, ts2 = 0.f;
#pragma unroll
        for (int w = 0; w < NW; ++w) { ts += sred[w][0][tid]; ts2 += sred[w][1][tid]; }
        atomicAdd(&stacc[bco * COT + tid], ts);
        atomicAdd(&stacc[COUT + bco * COT + tid], ts2);
    }
}

// ----------------------- conv2/conv3: K-split MFMA conv (partial out) -------
// Same pipeline as conv_mfma, but K-range split KS ways across blocks; each
// split writes its own partial buffer (no atomics). Stats done by consumer.
// Grid = KS x NM x NCO blocks of NW waves -> 8 waves/CU at 20KB LDS.
template <int CP, int COUT, int HP, int LOG_OHW, int LOG_OW, int SUB,
          int NM, int NCO, int NT, int CH, int NW, int KS>
__global__ __launch_bounds__(NW * 64) void conv_split(
        const unsigned short* __restrict__ inP,
        const unsigned short* __restrict__ wT,
        float* __restrict__ outP) {
    constexpr int NSTEP = 5 * SUB;
    constexpr int SSTEP = NSTEP / KS;
    constexpr int NCHUNK = SSTEP / CH;
    constexpr int COT = NT * 16;
    constexpr int NSTG = (CH * COT * 4) / (NW * 64);
    constexpr int M = NM * NW * 64;
    static_assert(NSTEP % KS == 0 && SSTEP % CH == 0, "split tiling");
    __shared__ short Bs[2][CH][COT][32];
    int tid = threadIdx.x;
    int wave = tid >> 6, lane = tid & 63, q = lane >> 4, l16 = lane & 15;
    int bidx = blockIdx.x;
    int ks = bidx / (NM * NCO);
    int rem = bidx - ks * (NM * NCO);
    int bm = rem / NCO, bco = rem % NCO;
    int sbase = ks * SSTEP;

    const short* aB[4];
#pragma unroll
    for (int f = 0; f < 4; ++f) {
        int m = bm * (NW * 64) + wave * 64 + f * 16 + l16;
        int b = m >> LOG_OHW;
        int ohw = m & ((1 << LOG_OHW) - 1);
        int oh = ohw >> LOG_OW, ow = ohw & ((1 << LOG_OW) - 1);
        aB[f] = (const short*)inP + ((size_t)((b * HP + 2 * oh) * HP + 2 * ow)) * CP + q * 8;
    }
    const short* bgbase = (const short*)wT + (size_t)bco * COT * 32;

    floatx4 acc[4][NT];
#pragma unroll
    for (int f = 0; f < 4; ++f)
#pragma unroll
        for (int nt = 0; nt < NT; ++nt) acc[f][nt] = (floatx4){0.f, 0.f, 0.f, 0.f};

    short8 nb[NSTG];
#pragma unroll
    for (int i = 0; i < NSTG; ++i) {
        int v = tid + i * NW * 64;
        int s = v / (COT * 4);
        int rem2 = v - s * (COT * 4);
        nb[i] = *(const short8*)(bgbase + ((size_t)(sbase + s) * COUT) * 32 + rem2 * 8);
    }
#pragma unroll
    for (int i = 0; i < NSTG; ++i) {
        int v = tid + i * NW * 64;
        int s = v / (COT * 4);
        int rem2 = v - s * (COT * 4);
        *(short8*)((short*)&Bs[0][s][0][0] + rem2 * 8) = nb[i];
    }
    __syncthreads();

    for (int chunk = 0; chunk < NCHUNK; ++chunk) {
        int cur = chunk & 1;
        if (chunk + 1 < NCHUNK) {
            int step0 = sbase + (chunk + 1) * CH;
#pragma unroll
            for (int i = 0; i < NSTG; ++i) {
                int v = tid + i * NW * 64;
                int s = v / (COT * 4);
                int rem2 = v - s * (COT * 4);
                nb[i] = *(const short8*)(bgbase + ((size_t)(step0 + s) * COUT) * 32 + rem2 * 8);
            }
        }
#pragma unroll
        for (int s = 0; s < CH; ++s) {
            int gstep = sbase + chunk * CH + s;
            int kh = gstep / SUB, sub = gstep - kh * SUB;
            short8 af[4];
#pragma unroll
            for (int f = 0; f < 4; ++f)
                af[f] = *(const short8*)(aB[f] + (size_t)(kh * HP) * CP + sub * 32);
#pragma unroll
            for (int nt = 0; nt < NT; ++nt) {
                short8 bf = *(const short8*)&Bs[cur][s][nt * 16 + l16][q * 8];
#pragma unroll
                for (int f = 0; f < 4; ++f)
                    acc[f][nt] = __builtin_amdgcn_mfma_f32_16x16x32_bf16(af[f], bf, acc[f][nt], 0, 0, 0);
            }
        }
        if (chunk + 1 < NCHUNK) {
#pragma unroll
            for (int i = 0; i < NSTG; ++i) {
                int v = tid + i * NW * 64;
                int s = v / (COT * 4);
                int rem2 = v - s * (COT * 4);
                *(short8*)((short*)&Bs[cur ^ 1][s][0][0] + rem2 * 8) = nb[i];
            }
            __syncthreads();
        }
    }
    float* outK = outP + (size_t)ks * M * COUT;
#pragma unroll
    for (int f = 0; f < 4; ++f)
#pragma unroll
        for (int nt = 0; nt < NT; ++nt)
#pragma unroll
            for (int rg = 0; rg < 4; ++rg) {
                int mg = bm * (NW * 64) + wave * 64 + f * 16 + q * 4 + rg;
                int co = bco * COT + nt * 16 + l16;
                outK[(size_t)mg * COUT + co] = acc[f][nt][rg];
            }
}

// --------------------------------------------------- conv4 split-K GEMM -----
__global__ __launch_bounds__(256) void conv4_mfma(const unsigned short* __restrict__ A,
                                                  const float* __restrict__ w4,
                                                  float* __restrict__ h4) {
    constexpr int CH = 4, NCHUNK = 8;
    __shared__ short Bs[CH][64][40];
    int tid = threadIdx.x;
    int bco = blockIdx.x & 15;
    int ks = blockIdx.x >> 4;
    int wave = tid >> 6, lane = tid & 63, q = lane >> 4, l16 = lane & 15;
    const short* aBase = (const short*)A + (size_t)(wave * 16 + l16) * 16384 + ks * 1024 + q * 8;
    int r = tid >> 2, cc = tid & 3;
    const float* bg = w4 + (size_t)(bco * 64 + r) * 16384 + ks * 1024 + cc * 8;

    floatx4 acc[4];
#pragma unroll
    for (int nt = 0; nt < 4; ++nt) acc[nt] = (floatx4){0.f, 0.f, 0.f, 0.f};

    short8 nb[CH];
#pragma unroll
    for (int s = 0; s < CH; ++s) {
        float4 b0 = *(const float4*)(bg + s * 32);
        float4 b1 = *(const float4*)(bg + s * 32 + 4);
        nb[s][0] = (short)f2bf(b0.x); nb[s][1] = (short)f2bf(b0.y);
        nb[s][2] = (short)f2bf(b0.z); nb[s][3] = (short)f2bf(b0.w);
        nb[s][4] = (short)f2bf(b1.x); nb[s][5] = (short)f2bf(b1.y);
        nb[s][6] = (short)f2bf(b1.z); nb[s][7] = (short)f2bf(b1.w);
    }
#pragma unroll
    for (int s = 0; s < CH; ++s) *(short8*)&Bs[s][r][cc * 8] = nb[s];
    __syncthreads();

    for (int chunk = 0; chunk < NCHUNK; ++chunk) {
        bool has_next = (chunk + 1 < NCHUNK);
        if (has_next) {
#pragma unroll
            for (int s = 0; s < CH; ++s) {
                int step = (chunk + 1) * CH + s;
                float4 b0 = *(const float4*)(bg + step * 32);
                float4 b1 = *(const float4*)(bg + step * 32 + 4);
                nb[s][0] = (short)f2bf(b0.x); nb[s][1] = (short)f2bf(b0.y);
                nb[s][2] = (short)f2bf(b0.z); nb[s][3] = (short)f2bf(b0.w);
                nb[s][4] = (short)f2bf(b1.x); nb[s][5] = (short)f2bf(b1.y);
                nb[s][6] = (short)f2bf(b1.z); nb[s][7] = (short)f2bf(b1.w);
            }
        }
#pragma unroll
        for (int s = 0; s < CH; ++s) {
            int step = chunk * CH + s;
            short8 af = *(const short8*)(aBase + step * 32);
#pragma unroll
            for (int nt = 0; nt < 4; ++nt) {
                short8 bf = *(const short8*)&Bs[s][nt * 16 + l16][q * 8];
                acc[nt] = __builtin_amdgcn_mfma_f32_16x16x32_bf16(af, bf, acc[nt], 0, 0, 0);
            }
        }
        if (has_next) {
            __syncthreads();
#pragma unroll
            for (int s = 0; s < CH; ++s) *(short8*)&Bs[s][r][cc * 8] = nb[s];
            __syncthreads();
        }
    }
#pragma unroll
    for (int nt = 0; nt < 4; ++nt) {
#pragma unroll
        for (int rg = 0; rg < 4; ++rg) {
            int mg = wave * 16 + q * 4 + rg;
            int co = bco * 64 + nt * 16 + l16;
            atomicAdd(&h4[(size_t)mg * 1024 + co], acc[nt][rg]);
        }
    }
}

// -------------------------------- batch stats (with k-split partial sum) ----
__global__ __launch_bounds__(256) void stats_part(const float* __restrict__ X,
                                                  float* __restrict__ acc,
                                                  int CO, int R, int RPB, int CGLOG,
                                                  int nsplit, size_t kstride) {
    int tid = threadIdx.x;
    int cg = blockIdx.x & ((1 << CGLOG) - 1);
    int rb = blockIdx.x >> CGLOG;
    int c = (cg << 6) + (tid & 63);
    int w = tid >> 6;
    float s = 0.f, s2 = 0.f;
    int rend = min(R, (rb + 1) * RPB);
    for (int r = rb * RPB + w; r < rend; r += 4) {
        float v = 0.f;
        for (int t = 0; t < nsplit; ++t) v += X[(size_t)t * kstride + (size_t)r * CO + c];
        s += v; s2 += v * v;
    }
    __shared__ float ls[4][64], ls2[4][64];
    ls[w][tid & 63] = s; ls2[w][tid & 63] = s2;
    __syncthreads();
    if (tid < 64) {
        float ts = ls[0][tid] + ls[1][tid] + ls[2][tid] + ls[3][tid];
        float ts2 = ls2[0][tid] + ls2[1][tid] + ls2[2][tid] + ls2[3][tid];
        int cc = (cg << 6) + tid;
        atomicAdd(&acc[cc], ts);
        atomicAdd(&acc[CO + cc], ts2);
    }
}

// ---------- BN(inline finalize) + lrelu + pad + bf16 (k-split sum, NHWC) ----
__global__ __launch_bounds__(256) void bnpad_kernel(const float* __restrict__ X,
                                                    const float* __restrict__ stacc,
                                                    const float* __restrict__ g,
                                                    const float* __restrict__ bb,
                                                    unsigned short* __restrict__ out,
                                                    int CO_LOG, int OH, int OHP,
                                                    float invN, int total,
                                                    int nsplit, size_t kstride) {
    int idx = blockIdx.x * 256 + threadIdx.x;
    if (idx >= total) return;
    int CO = 1 << CO_LOG;
    int c = idx & (CO - 1);
    float mean = stacc[c] * invN;
    float var = fmaxf(stacc[CO + c] * invN - mean * mean, 0.f);
    float sc = g[c] * rsqrtf(var + EPS);
    float sh = bb[c] - mean * sc;
    int t = idx >> CO_LOG;
    int x = t % OHP; t /= OHP;
    int y = t % OHP; int b = t / OHP;
    unsigned short v = 0;
    if (y >= 2 && y < OH + 2 && x >= 2 && x < OH + 2) {
        size_t base = (((size_t)(b * OH + (y - 2)) * OH + (x - 2)) << CO_LOG) + c;
        float f = 0.f;
        for (int ts = 0; ts < nsplit; ++ts) f += X[base + (size_t)ts * kstride];
        f = f * sc + sh;
        f = f >= 0.f ? f : NEG * f;
        v = f2bf(f);
    }
    out[idx] = v;
}

// ---- BN(inline) + lrelu + bf16, NHWC(k-split sum) -> NCHW (conv4 input) ----
__global__ __launch_bounds__(256) void bn_nchw_kernel(const float* __restrict__ X,
                                                      const float* __restrict__ stacc,
                                                      const float* __restrict__ g,
                                                      const float* __restrict__ bb,
                                                      unsigned short* __restrict__ out,
                                                      int total, int nsplit, size_t kstride) {
    int idx = blockIdx.x * 256 + threadIdx.x;
    if (idx >= total) return;
    int hw = idx & 63;
    int ci = (idx >> 6) & 255;
    int b = idx >> 14;
    float mean = stacc[ci] * (1.f / 4096.f);
    float var = fmaxf(stacc[256 + ci] * (1.f / 4096.f) - mean * mean, 0.f);
    float sc = g[ci] * rsqrtf(var + EPS);
    float sh = bb[ci] - mean * sc;
    size_t base = ((size_t)(b * 64 + hw)) * 256 + ci;
    float f = 0.f;
    for (int ts = 0; ts < nsplit; ++ts) f += X[base + (size_t)ts * kstride];
    f = f * sc + sh;
    f = f >= 0.f ? f : NEG * f;
    out[idx] = f2bf(f);
}

// -------------------------------------- conv5 (inline BN4 finalize) ---------
__global__ __launch_bounds__(256) void conv5_kernel(const float* __restrict__ X,
                                                    const float* __restrict__ stacc,
                                                    const float* __restrict__ g,
                                                    const float* __restrict__ bb,
                                                    const float* __restrict__ w5,
                                                    const float* __restrict__ b5,
                                                    float* __restrict__ out) {
    int b = blockIdx.x, tid = threadIdx.x;
    float s = 0.f;
    for (int c = tid; c < 1024; c += 256) {
        float mean = stacc[c] * (1.f / 64.f);
        float var = fmaxf(stacc[1024 + c] * (1.f / 64.f) - mean * mean, 0.f);
        float sc = g[c] * rsqrtf(var + EPS);
        float sh = bb[c] - mean * sc;
        float f = X[(size_t)b * 1024 + c] * sc + sh;
        f = f >= 0.f ? f : NEG * f;
        s = fmaf(f, w5[c], s);
    }
#pragma unroll
    for (int off = 32; off > 0; off >>= 1) s += __shfl_down(s, off);
    __shared__ float ls[4];
    if ((tid & 63) == 0) ls[tid >> 6] = s;
    __syncthreads();
    if (tid == 0) out[b] = ls[0] + ls[1] + ls[2] + ls[3] + b5[0];
}

// ----------------------------------------------------------------- launch ---
extern "C" void kernel_launch(void* const* d_in, const int* in_sizes, int n_in,
                              void* d_out, int out_size, void* d_ws, size_t ws_size,
                              hipStream_t stream) {
    (void)in_sizes; (void)n_in; (void)out_size; (void)ws_size;
    const float* input_data = (const float*)d_in[0];
    const float* w1 = (const float*)d_in[2];
    const float* g1 = (const float*)d_in[3];
    const float* b1 = (const float*)d_in[4];
    const float* w2 = (const float*)d_in[5];
    const float* g2 = (const float*)d_in[6];
    const float* b2 = (const float*)d_in[7];
    const float* w3 = (const float*)d_in[8];
    const float* g3 = (const float*)d_in[9];
    const float* b3 = (const float*)d_in[10];
    const float* w4 = (const float*)d_in[11];
    const float* g4 = (const float*)d_in[12];
    const float* b4 = (const float*)d_in[13];
    const float* w5 = (const float*)d_in[14];
    const float* b5 = (const float*)d_in[15];

    char* ws = (char*)d_ws;
    // fully de-aliased layout (uses 81 MB of 256 MiB workspace)
    unsigned short* rendered   = (unsigned short*)(ws + 0);          //  9,469,952
    float*          conv1out   = (float*)(ws + 9469952);             // 16,777,216
    unsigned short* pad1       = (unsigned short*)(ws + 26247168);   // 10,616,832
    float*          conv2parts = (float*)(ws + 36864000);            // 16,777,216 (2 splits)
    unsigned short* pad2       = (unsigned short*)(ws + 53641216);   //  6,553,600
    float*          conv3parts = (float*)(ws + 60194816);            // 16,777,216 (4 splits)
    unsigned short* a4         = (unsigned short*)(ws + 76972032);   //  2,097,152
    float*          h4         = (float*)(ws + 79069184);            //    262,144
    float*          st1        = (float*)(ws + 79331328);            //        512
    float*          st2        = (float*)(ws + 79331840);            //      1,024
    float*          st3        = (float*)(ws + 79332864);            //      2,048
    float*          st4        = (float*)(ws + 79334912);            //      8,192
    unsigned short* wT1        = (unsigned short*)(ws + 79343104);   //     61,440
    unsigned short* wT2        = (unsigned short*)(ws + 79404544);   //    409,600
    unsigned short* wT3        = (unsigned short*)(ws + 79814144);   //  1,638,400

    // one memset: h4 + st1..st4
    hipMemsetAsync(ws + 79069184, 0, 273920, stream);
    wtrans_all<<<4120, 256, 0, stream>>>(w1, w2, w3, wT1, wT2, wT3);
    render_kernel<<<1024, 256, 0, stream>>>(input_data, rendered);

    // conv1: [65536,480]x[480,64] — 256 blocks x 4 waves, NT=4, CH=5, fused stats
    conv_mfma<16, 64, 68, 10, 5, 3, 1, 4, 5, 4><<<256, 256, 0, stream>>>(rendered, wT1, conv1out, st1);
    bnpad_kernel<<<20736, 256, 0, stream>>>(conv1out, st1, g1, b1, pad1, 6, 32, 36,
                                            1.f / 65536.f, 5308416, 1, 0);

    // conv2: [16384,1600]x[1600,128] — KS=2: 2x128x4 = 1024 blocks x 2 waves (8 w/CU)
    conv_split<64, 128, 36, 8, 4, 10, 128, 4, 2, 5, 2, 2><<<1024, 128, 0, stream>>>(pad1, wT2, conv2parts);
    stats_part<<<256, 256, 0, stream>>>(conv2parts, st2, 128, 16384, 128, 1, 2, 2097152);
    bnpad_kernel<<<12800, 256, 0, stream>>>(conv2parts, st2, g2, b2, pad2, 7, 16, 20,
                                            1.f / 16384.f, 3276800, 2, 2097152);

    // conv3: [4096,3200]x[3200,256] — KS=4: 4x32x8 = 1024 blocks x 2 waves (8 w/CU)
    conv_split<128, 256, 20, 6, 3, 20, 32, 8, 2, 5, 2, 4><<<1024, 128, 0, stream>>>(pad2, wT3, conv3parts);
    stats_part<<<512, 256, 0, stream>>>(conv3parts, st3, 256, 4096, 32, 2, 4, 1048576);
    bn_nchw_kernel<<<4096, 256, 0, stream>>>(conv3parts, st3, g3, b3, a4, 1048576, 4, 1048576);

    // conv4: [64,16384] x [1024,16384]^T -> [64,1024], split-K=16 (atomic h4)
    conv4_mfma<<<256, 256, 0, stream>>>(a4, w4, h4);
    stats_part<<<16, 256, 0, stream>>>(h4, st4, 1024, 64, 64, 4, 1, 0);

    // conv5 (inline BN4)
    conv5_kernel<<<64, 256, 0, stream>>>(h4, st4, g4, b4, w5, b5, (float*)d_out);
}

// Round 9
// 280.642 us; speedup vs baseline: 1.3018x; 1.1351x over previous
//
#include <hip/hip_runtime.h>
#include <hip/hip_bf16.h>

#define NEG 0.01f
#define EPS 1e-5f

typedef __attribute__((ext_vector_type(8))) short short8;
typedef __attribute__((ext_vector_type(4))) float floatx4;

__device__ inline unsigned short f2bf(float f) {
    __hip_bfloat16 h = __float2bfloat16(f);
    union { __hip_bfloat16 h; unsigned short u; } cv; cv.h = h;
    return cv.u;
}

// ------------------------- fused render + weight transform (1 dispatch) ----
// blocks [0,1024): render -> padded NHWC bf16 [64][68][68][16] incl. borders
// blocks [1024,5144): wT transforms for w1/w2/w3
__global__ __launch_bounds__(256) void prep_kernel(const float* __restrict__ in,
                                                   unsigned short* __restrict__ out,
                                                   const float* __restrict__ w1,
                                                   const float* __restrict__ w2,
                                                   const float* __restrict__ w3,
                                                   unsigned short* __restrict__ wT1,
                                                   unsigned short* __restrict__ wT2,
                                                   unsigned short* __restrict__ wT3) {
    int tid = threadIdx.x;
    if (blockIdx.x >= 1024) {
        int idx = (blockIdx.x - 1024) * 256 + tid;
        const float* w; unsigned short* wT; int CIN, CPLOG, SUB, COLOG;
        if (idx < 30720) { w = w1; wT = wT1; CIN = 14; CPLOG = 4; SUB = 3; COLOG = 6; }
        else if (idx < 235520) { idx -= 30720; w = w2; wT = wT2; CIN = 64; CPLOG = 6; SUB = 10; COLOG = 7; }
        else if (idx < 1054720) { idx -= 235520; w = w3; wT = wT3; CIN = 128; CPLOG = 7; SUB = 20; COLOG = 8; }
        else return;
        int kk = idx & 31;
        int co = (idx >> 5) & ((1 << COLOG) - 1);
        int s = idx >> (5 + COLOG);
        int kh = s / SUB, sub = s - kh * SUB;
        int kidx = sub * 32 + kk;
        int kw = kidx >> CPLOG;
        int ci = kidx & ((1 << CPLOG) - 1);
        float v = (kw < 5 && ci < CIN) ? w[((size_t)(co * CIN + ci) * 5 + kh) * 5 + kw] : 0.f;
        wT[idx] = f2bf(v);
        return;
    }
    int b = blockIdx.x >> 4;
    int chunk = blockIdx.x & 15;
    __shared__ float r0[46], r1[46], r2[46], r3[46];
    __shared__ float cls_s[46 * 14];
    if (tid < 46) {
        const float* p = in + ((size_t)b * 46 + tid) * 18 + 14;
        float x = p[0] * 64.f, y = p[1] * 64.f, w = p[2] * 64.f, h = p[3] * 64.f;
        r0[tid] = x - 0.5f * w; r1[tid] = x + 0.5f * w;
        r2[tid] = y - 0.5f * h; r3[tid] = y + 0.5f * h;
    }
    for (int idx = tid; idx < 46 * 14; idx += 256) {
        int n = idx / 14, c = idx % 14;
        cls_s[idx] = in[((size_t)b * 46 + n) * 18 + c];
    }
    __syncthreads();
    if (tid < 33) {
        int j = chunk * 33 + tid;
        if (j < 528) {
            int y, x;
            if (j < 136) { y = j / 68; x = j - y * 68; }
            else if (j < 272) { int t = j - 136; int yy = t / 68; y = 66 + yy; x = t - yy * 68; }
            else { int t = j - 272; y = 2 + (t >> 2); int k = t & 3; x = (k < 2) ? k : 64 + k; }
            size_t zb = (((size_t)b * 68 + y) * 68 + x) * 16;
            short8 z;
#pragma unroll
            for (int i = 0; i < 8; ++i) z[i] = 0;
            *(short8*)(out + zb) = z;
            *(short8*)(out + zb + 8) = z;
        }
    }
    int pix = chunk * 256 + tid;
    float cx = (float)(pix & 63);
    float cy = (float)(pix >> 6);
    float acc[14];
#pragma unroll
    for (int c = 0; c < 14; ++c) acc[c] = 0.f;
    for (int n = 0; n < 46; ++n) {
        float x0 = r0[n], x1 = r1[n], y0 = r2[n], y1 = r3[n];
        float by = fminf(fmaxf(cy - y0, 0.f), 1.f) * fminf(fmaxf(y1 - cy, 0.f), 1.f);
        float bx = fminf(fmaxf(cx - x0, 0.f), 1.f) * fminf(fmaxf(x1 - cx, 0.f), 1.f);
        float kx0 = fmaxf(1.f - fabsf(cx - x0), 0.f);
        float kx1 = fmaxf(1.f - fabsf(cx - x1), 0.f);
        float ky0 = fmaxf(1.f - fabsf(cy - y0), 0.f);
        float ky1 = fmaxf(1.f - fabsf(cy - y1), 0.f);
        float r = fmaxf(fmaxf(kx0 * by, kx1 * by), fmaxf(ky0 * bx, ky1 * bx));
        if (r > 0.f) {
#pragma unroll
            for (int c = 0; c < 14; ++c) acc[c] = fmaf(cls_s[n * 14 + c], r, acc[c]);
        }
    }
    size_t obase = (((size_t)b * 68 + ((pix >> 6) + 2)) * 68 + ((pix & 63) + 2)) * 16;
    short8 v0, v1;
#pragma unroll
    for (int i = 0; i < 8; ++i) v0[i] = (short)f2bf(acc[i]);
#pragma unroll
    for (int i = 0; i < 6; ++i) v1[i] = (short)f2bf(acc[8 + i]);
    v1[6] = 0; v1[7] = 0;
    *(short8*)(out + obase) = v0;
    *(short8*)(out + obase + 8) = v1;
}

// ------------------------- conv1/conv2: MFMA conv + fused BN stats (R5) ----
template <int CP, int COUT, int HP, int LOG_OHW, int LOG_OW, int SUB,
          int NCO, int NT, int CH, int NW>
__global__ __launch_bounds__(NW * 64) void conv_mfma(
        const unsigned short* __restrict__ inP,
        const unsigned short* __restrict__ wT,
        float* __restrict__ outX,
        float* __restrict__ stacc) {
    constexpr int NSTEP = 5 * SUB;
    constexpr int NCHUNK = NSTEP / CH;
    constexpr int COT = NT * 16;
    constexpr int NSTG = (CH * COT * 4) / (NW * 64);
    __shared__ short Bs[2][CH][COT][32];
    __shared__ float sred[NW][2][COT];
    int tid = threadIdx.x;
    int wave = tid >> 6, lane = tid & 63, q = lane >> 4, l16 = lane & 15;
    int bm = blockIdx.x / NCO, bco = blockIdx.x % NCO;

    const short* aB[4];
#pragma unroll
    for (int f = 0; f < 4; ++f) {
        int m = bm * (NW * 64) + wave * 64 + f * 16 + l16;
        int b = m >> LOG_OHW;
        int ohw = m & ((1 << LOG_OHW) - 1);
        int oh = ohw >> LOG_OW, ow = ohw & ((1 << LOG_OW) - 1);
        aB[f] = (const short*)inP + ((size_t)((b * HP + 2 * oh) * HP + 2 * ow)) * CP + q * 8;
    }
    const short* bgbase = (const short*)wT + (size_t)bco * COT * 32;

    floatx4 acc[4][NT];
#pragma unroll
    for (int f = 0; f < 4; ++f)
#pragma unroll
        for (int nt = 0; nt < NT; ++nt) acc[f][nt] = (floatx4){0.f, 0.f, 0.f, 0.f};

    short8 nb[NSTG];
#pragma unroll
    for (int i = 0; i < NSTG; ++i) {
        int v = tid + i * NW * 64;
        int s = v / (COT * 4);
        int rem = v - s * (COT * 4);
        nb[i] = *(const short8*)(bgbase + ((size_t)s * COUT) * 32 + rem * 8);
    }
#pragma unroll
    for (int i = 0; i < NSTG; ++i) {
        int v = tid + i * NW * 64;
        int s = v / (COT * 4);
        int rem = v - s * (COT * 4);
        *(short8*)((short*)&Bs[0][s][0][0] + rem * 8) = nb[i];
    }
    __syncthreads();

    for (int chunk = 0; chunk < NCHUNK; ++chunk) {
        int cur = chunk & 1;
        if (chunk + 1 < NCHUNK) {
            int step0 = (chunk + 1) * CH;
#pragma unroll
            for (int i = 0; i < NSTG; ++i) {
                int v = tid + i * NW * 64;
                int s = v / (COT * 4);
                int rem = v - s * (COT * 4);
                nb[i] = *(const short8*)(bgbase + ((size_t)(step0 + s) * COUT) * 32 + rem * 8);
            }
        }
#pragma unroll
        for (int s = 0; s < CH; ++s) {
            int step = chunk * CH + s;
            int kh = step / SUB, sub = step - kh * SUB;
            short8 af[4];
#pragma unroll
            for (int f = 0; f < 4; ++f)
                af[f] = *(const short8*)(aB[f] + (size_t)(kh * HP) * CP + sub * 32);
#pragma unroll
            for (int nt = 0; nt < NT; ++nt) {
                short8 bf = *(const short8*)&Bs[cur][s][nt * 16 + l16][q * 8];
#pragma unroll
                for (int f = 0; f < 4; ++f)
                    acc[f][nt] = __builtin_amdgcn_mfma_f32_16x16x32_bf16(af[f], bf, acc[f][nt], 0, 0, 0);
            }
        }
        if (chunk + 1 < NCHUNK) {
#pragma unroll
            for (int i = 0; i < NSTG; ++i) {
                int v = tid + i * NW * 64;
                int s = v / (COT * 4);
                int rem = v - s * (COT * 4);
                *(short8*)((short*)&Bs[cur ^ 1][s][0][0] + rem * 8) = nb[i];
            }
            __syncthreads();
        }
    }
#pragma unroll
    for (int f = 0; f < 4; ++f)
#pragma unroll
        for (int nt = 0; nt < NT; ++nt)
#pragma unroll
            for (int rg = 0; rg < 4; ++rg) {
                int mg = bm * (NW * 64) + wave * 64 + f * 16 + q * 4 + rg;
                int co = bco * COT + nt * 16 + l16;
                outX[(size_t)mg * COUT + co] = acc[f][nt][rg];
            }
#pragma unroll
    for (int nt = 0; nt < NT; ++nt) {
        float s = 0.f, s2 = 0.f;
#pragma unroll
        for (int f = 0; f < 4; ++f)
#pragma unroll
            for (int rg = 0; rg < 4; ++rg) {
                float v = acc[f][nt][rg];
                s += v; s2 = fmaf(v, v, s2);
            }
        s += __shfl_xor(s, 16); s += __shfl_xor(s, 32);
        s2 += __shfl_xor(s2, 16); s2 += __shfl_xor(s2, 32);
        if (q == 0) {
            sred[wave][0][nt * 16 + l16] = s;
            sred[wave][1][nt * 16 + l16] = s2;
        }
    }
    __syncthreads();
    if (tid < COT) {
        float ts = 0.f, ts2 = 0.f;
#pragma unroll
        for (int w = 0; w < NW; ++w) { ts += sred[w][0][tid]; ts2 += sred[w][1][tid]; }
        atomicAdd(&stacc[bco * COT + tid], ts);
        atomicAdd(&stacc[COUT + bco * COT + tid], ts2);
    }
}

// -------------------------- conv3: K-split MFMA conv (partial outputs) ------
template <int CP, int COUT, int HP, int LOG_OHW, int LOG_OW, int SUB,
          int NM, int NCO, int NT, int CH, int NW, int KS>
__global__ __launch_bounds__(NW * 64) void conv_split(
        const unsigned short* __restrict__ inP,
        const unsigned short* __restrict__ wT,
        float* __restrict__ outP) {
    constexpr int NSTEP = 5 * SUB;
    constexpr int SSTEP = NSTEP / KS;
    constexpr int NCHUNK = SSTEP / CH;
    constexpr int COT = NT * 16;
    constexpr int NSTG = (CH * COT * 4) / (NW * 64);
    constexpr int M = NM * NW * 64;
    static_assert(NSTEP % KS == 0 && SSTEP % CH == 0, "split tiling");
    __shared__ short Bs[2][CH][COT][32];
    int tid = threadIdx.x;
    int wave = tid >> 6, lane = tid & 63, q = lane >> 4, l16 = lane & 15;
    int bidx = blockIdx.x;
    int ks = bidx / (NM * NCO);
    int rem = bidx - ks * (NM * NCO);
    int bm = rem / NCO, bco = rem % NCO;
    int sbase = ks * SSTEP;

    const short* aB[4];
#pragma unroll
    for (int f = 0; f < 4; ++f) {
        int m = bm * (NW * 64) + wave * 64 + f * 16 + l16;
        int b = m >> LOG_OHW;
        int ohw = m & ((1 << LOG_OHW) - 1);
        int oh = ohw >> LOG_OW, ow = ohw & ((1 << LOG_OW) - 1);
        aB[f] = (const short*)inP + ((size_t)((b * HP + 2 * oh) * HP + 2 * ow)) * CP + q * 8;
    }
    const short* bgbase = (const short*)wT + (size_t)bco * COT * 32;

    floatx4 acc[4][NT];
#pragma unroll
    for (int f = 0; f < 4; ++f)
#pragma unroll
        for (int nt = 0; nt < NT; ++nt) acc[f][nt] = (floatx4){0.f, 0.f, 0.f, 0.f};

    short8 nb[NSTG];
#pragma unroll
    for (int i = 0; i < NSTG; ++i) {
        int v = tid + i * NW * 64;
        int s = v / (COT * 4);
        int rem2 = v - s * (COT * 4);
        nb[i] = *(const short8*)(bgbase + ((size_t)(sbase + s) * COUT) * 32 + rem2 * 8);
    }
#pragma unroll
    for (int i = 0; i < NSTG; ++i) {
        int v = tid + i * NW * 64;
        int s = v / (COT * 4);
        int rem2 = v - s * (COT * 4);
        *(short8*)((short*)&Bs[0][s][0][0] + rem2 * 8) = nb[i];
    }
    __syncthreads();

    for (int chunk = 0; chunk < NCHUNK; ++chunk) {
        int cur = chunk & 1;
        if (chunk + 1 < NCHUNK) {
            int step0 = sbase + (chunk + 1) * CH;
#pragma unroll
            for (int i = 0; i < NSTG; ++i) {
                int v = tid + i * NW * 64;
                int s = v / (COT * 4);
                int rem2 = v - s * (COT * 4);
                nb[i] = *(const short8*)(bgbase + ((size_t)(step0 + s) * COUT) * 32 + rem2 * 8);
            }
        }
#pragma unroll
        for (int s = 0; s < CH; ++s) {
            int gstep = sbase + chunk * CH + s;
            int kh = gstep / SUB, sub = gstep - kh * SUB;
            short8 af[4];
#pragma unroll
            for (int f = 0; f < 4; ++f)
                af[f] = *(const short8*)(aB[f] + (size_t)(kh * HP) * CP + sub * 32);
#pragma unroll
            for (int nt = 0; nt < NT; ++nt) {
                short8 bf = *(const short8*)&Bs[cur][s][nt * 16 + l16][q * 8];
#pragma unroll
                for (int f = 0; f < 4; ++f)
                    acc[f][nt] = __builtin_amdgcn_mfma_f32_16x16x32_bf16(af[f], bf, acc[f][nt], 0, 0, 0);
            }
        }
        if (chunk + 1 < NCHUNK) {
#pragma unroll
            for (int i = 0; i < NSTG; ++i) {
                int v = tid + i * NW * 64;
                int s = v / (COT * 4);
                int rem2 = v - s * (COT * 4);
                *(short8*)((short*)&Bs[cur ^ 1][s][0][0] + rem2 * 8) = nb[i];
            }
            __syncthreads();
        }
    }
    float* outK = outP + (size_t)ks * M * COUT;
#pragma unroll
    for (int f = 0; f < 4; ++f)
#pragma unroll
        for (int nt = 0; nt < NT; ++nt)
#pragma unroll
            for (int rg = 0; rg < 4; ++rg) {
                int mg = bm * (NW * 64) + wave * 64 + f * 16 + q * 4 + rg;
                int co = bco * COT + nt * 16 + l16;
                outK[(size_t)mg * COUT + co] = acc[f][nt][rg];
            }
}

// --------------------------------------------------- conv4 split-K GEMM -----
__global__ __launch_bounds__(256) void conv4_mfma(const unsigned short* __restrict__ A,
                                                  const float* __restrict__ w4,
                                                  float* __restrict__ h4) {
    constexpr int CH = 4, NCHUNK = 8;
    __shared__ short Bs[CH][64][40];
    int tid = threadIdx.x;
    int bco = blockIdx.x & 15;
    int ks = blockIdx.x >> 4;
    int wave = tid >> 6, lane = tid & 63, q = lane >> 4, l16 = lane & 15;
    const short* aBase = (const short*)A + (size_t)(wave * 16 + l16) * 16384 + ks * 1024 + q * 8;
    int r = tid >> 2, cc = tid & 3;
    const float* bg = w4 + (size_t)(bco * 64 + r) * 16384 + ks * 1024 + cc * 8;

    floatx4 acc[4];
#pragma unroll
    for (int nt = 0; nt < 4; ++nt) acc[nt] = (floatx4){0.f, 0.f, 0.f, 0.f};

    short8 nb[CH];
#pragma unroll
    for (int s = 0; s < CH; ++s) {
        float4 b0 = *(const float4*)(bg + s * 32);
        float4 b1 = *(const float4*)(bg + s * 32 + 4);
        nb[s][0] = (short)f2bf(b0.x); nb[s][1] = (short)f2bf(b0.y);
        nb[s][2] = (short)f2bf(b0.z); nb[s][3] = (short)f2bf(b0.w);
        nb[s][4] = (short)f2bf(b1.x); nb[s][5] = (short)f2bf(b1.y);
        nb[s][6] = (short)f2bf(b1.z); nb[s][7] = (short)f2bf(b1.w);
    }
#pragma unroll
    for (int s = 0; s < CH; ++s) *(short8*)&Bs[s][r][cc * 8] = nb[s];
    __syncthreads();

    for (int chunk = 0; chunk < NCHUNK; ++chunk) {
        bool has_next = (chunk + 1 < NCHUNK);
        if (has_next) {
#pragma unroll
            for (int s = 0; s < CH; ++s) {
                int step = (chunk + 1) * CH + s;
                float4 b0 = *(const float4*)(bg + step * 32);
                float4 b1 = *(const float4*)(bg + step * 32 + 4);
                nb[s][0] = (short)f2bf(b0.x); nb[s][1] = (short)f2bf(b0.y);
                nb[s][2] = (short)f2bf(b0.z); nb[s][3] = (short)f2bf(b0.w);
                nb[s][4] = (short)f2bf(b1.x); nb[s][5] = (short)f2bf(b1.y);
                nb[s][6] = (short)f2bf(b1.z); nb[s][7] = (short)f2bf(b1.w);
            }
        }
#pragma unroll
        for (int s = 0; s < CH; ++s) {
            int step = chunk * CH + s;
            short8 af = *(const short8*)(aBase + step * 32);
#pragma unroll
            for (int nt = 0; nt < 4; ++nt) {
                short8 bf = *(const short8*)&Bs[s][nt * 16 + l16][q * 8];
                acc[nt] = __builtin_amdgcn_mfma_f32_16x16x32_bf16(af, bf, acc[nt], 0, 0, 0);
            }
        }
        if (has_next) {
            __syncthreads();
#pragma unroll
            for (int s = 0; s < CH; ++s) *(short8*)&Bs[s][r][cc * 8] = nb[s];
            __syncthreads();
        }
    }
#pragma unroll
    for (int nt = 0; nt < 4; ++nt) {
#pragma unroll
        for (int rg = 0; rg < 4; ++rg) {
            int mg = wave * 16 + q * 4 + rg;
            int co = bco * 64 + nt * 16 + l16;
            atomicAdd(&h4[(size_t)mg * 1024 + co], acc[nt][rg]);
        }
    }
}

// -------------------------------- batch stats (with k-split partial sum) ----
__global__ __launch_bounds__(256) void stats_part(const float* __restrict__ X,
                                                  float* __restrict__ acc,
                                                  int CO, int R, int RPB, int CGLOG,
                                                  int nsplit, size_t kstride) {
    int tid = threadIdx.x;
    int cg = blockIdx.x & ((1 << CGLOG) - 1);
    int rb = blockIdx.x >> CGLOG;
    int c = (cg << 6) + (tid & 63);
    int w = tid >> 6;
    float s = 0.f, s2 = 0.f;
    int rend = min(R, (rb + 1) * RPB);
    for (int r = rb * RPB + w; r < rend; r += 4) {
        float v = 0.f;
        for (int t = 0; t < nsplit; ++t) v += X[(size_t)t * kstride + (size_t)r * CO + c];
        s += v; s2 += v * v;
    }
    __shared__ float ls[4][64], ls2[4][64];
    ls[w][tid & 63] = s; ls2[w][tid & 63] = s2;
    __syncthreads();
    if (tid < 64) {
        float ts = ls[0][tid] + ls[1][tid] + ls[2][tid] + ls[3][tid];
        float ts2 = ls2[0][tid] + ls2[1][tid] + ls2[2][tid] + ls2[3][tid];
        int cc = (cg << 6) + tid;
        atomicAdd(&acc[cc], ts);
        atomicAdd(&acc[CO + cc], ts2);
    }
}

// ------------------- BN(inline finalize) + lrelu + pad + bf16 (NHWC) --------
__global__ __launch_bounds__(256) void bnpad_kernel(const float* __restrict__ X,
                                                    const float* __restrict__ stacc,
                                                    const float* __restrict__ g,
                                                    const float* __restrict__ bb,
                                                    unsigned short* __restrict__ out,
                                                    int CO_LOG, int OH, int OHP,
                                                    float invN, int total) {
    int idx = blockIdx.x * 256 + threadIdx.x;
    if (idx >= total) return;
    int CO = 1 << CO_LOG;
    int c = idx & (CO - 1);
    float mean = stacc[c] * invN;
    float var = fmaxf(stacc[CO + c] * invN - mean * mean, 0.f);
    float sc = g[c] * rsqrtf(var + EPS);
    float sh = bb[c] - mean * sc;
    int t = idx >> CO_LOG;
    int x = t % OHP; t /= OHP;
    int y = t % OHP; int b = t / OHP;
    unsigned short v = 0;
    if (y >= 2 && y < OH + 2 && x >= 2 && x < OH + 2) {
        float f = X[(((size_t)(b * OH + (y - 2)) * OH + (x - 2)) << CO_LOG) + c];
        f = f * sc + sh;
        f = f >= 0.f ? f : NEG * f;
        v = f2bf(f);
    }
    out[idx] = v;
}

// ---- BN(inline) + lrelu + bf16, NHWC(k-split sum) -> NCHW (conv4 input) ----
__global__ __launch_bounds__(256) void bn_nchw_kernel(const float* __restrict__ X,
                                                      const float* __restrict__ stacc,
                                                      const float* __restrict__ g,
                                                      const float* __restrict__ bb,
                                                      unsigned short* __restrict__ out,
                                                      int total, int nsplit, size_t kstride) {
    int idx = blockIdx.x * 256 + threadIdx.x;
    if (idx >= total) return;
    int hw = idx & 63;
    int ci = (idx >> 6) & 255;
    int b = idx >> 14;
    float mean = stacc[ci] * (1.f / 4096.f);
    float var = fmaxf(stacc[256 + ci] * (1.f / 4096.f) - mean * mean, 0.f);
    float sc = g[ci] * rsqrtf(var + EPS);
    float sh = bb[ci] - mean * sc;
    size_t base = ((size_t)(b * 64 + hw)) * 256 + ci;
    float f = 0.f;
    for (int ts = 0; ts < nsplit; ++ts) f += X[base + (size_t)ts * kstride];
    f = f * sc + sh;
    f = f >= 0.f ? f : NEG * f;
    out[idx] = f2bf(f);
}

// -------------------------------------- conv5 (inline BN4 finalize) ---------
__global__ __launch_bounds__(256) void conv5_kernel(const float* __restrict__ X,
                                                    const float* __restrict__ stacc,
                                                    const float* __restrict__ g,
                                                    const float* __restrict__ bb,
                                                    const float* __restrict__ w5,
                                                    const float* __restrict__ b5,
                                                    float* __restrict__ out) {
    int b = blockIdx.x, tid = threadIdx.x;
    float s = 0.f;
    for (int c = tid; c < 1024; c += 256) {
        float mean = stacc[c] * (1.f / 64.f);
        float var = fmaxf(stacc[1024 + c] * (1.f / 64.f) - mean * mean, 0.f);
        float sc = g[c] * rsqrtf(var + EPS);
        float sh = bb[c] - mean * sc;
        float f = X[(size_t)b * 1024 + c] * sc + sh;
        f = f >= 0.f ? f : NEG * f;
        s = fmaf(f, w5[c], s);
    }
#pragma unroll
    for (int off = 32; off > 0; off >>= 1) s += __shfl_down(s, off);
    __shared__ float ls[4];
    if ((tid & 63) == 0) ls[tid >> 6] = s;
    __syncthreads();
    if (tid == 0) out[b] = ls[0] + ls[1] + ls[2] + ls[3] + b5[0];
}

// ----------------------------------------------------------------- launch ---
extern "C" void kernel_launch(void* const* d_in, const int* in_sizes, int n_in,
                              void* d_out, int out_size, void* d_ws, size_t ws_size,
                              hipStream_t stream) {
    (void)in_sizes; (void)n_in; (void)out_size; (void)ws_size;
    const float* input_data = (const float*)d_in[0];
    const float* w1 = (const float*)d_in[2];
    const float* g1 = (const float*)d_in[3];
    const float* b1 = (const float*)d_in[4];
    const float* w2 = (const float*)d_in[5];
    const float* g2 = (const float*)d_in[6];
    const float* b2 = (const float*)d_in[7];
    const float* w3 = (const float*)d_in[8];
    const float* g3 = (const float*)d_in[9];
    const float* b3 = (const float*)d_in[10];
    const float* w4 = (const float*)d_in[11];
    const float* g4 = (const float*)d_in[12];
    const float* b4 = (const float*)d_in[13];
    const float* w5 = (const float*)d_in[14];
    const float* b5 = (const float*)d_in[15];

    char* ws = (char*)d_ws;
    unsigned short* rendered   = (unsigned short*)(ws + 0);          //  9,469,952
    float*          conv1out   = (float*)(ws + 9469952);             // 16,777,216
    unsigned short* pad1       = (unsigned short*)(ws + 26247168);   // 10,616,832
    float*          conv2out   = (float*)(ws + 36864000);            //  8,388,608
    unsigned short* pad2       = (unsigned short*)(ws + 45252608);   //  6,553,600
    float*          conv3parts = (float*)(ws + 51806208);            //  8,388,608 (2 splits)
    unsigned short* a4         = (unsigned short*)(ws + 60194816);   //  2,097,152
    float*          h4         = (float*)(ws + 62291968);            //    262,144
    float*          st1        = (float*)(ws + 62554112);            //        512
    float*          st2        = (float*)(ws + 62554624);            //      1,024
    float*          st3        = (float*)(ws + 62555648);            //      2,048
    float*          st4        = (float*)(ws + 62557696);            //      8,192
    unsigned short* wT1        = (unsigned short*)(ws + 62565888);   //     61,440
    unsigned short* wT2        = (unsigned short*)(ws + 62627328);   //    409,600
    unsigned short* wT3        = (unsigned short*)(ws + 63036928);   //  1,638,400

    // one memset: h4 + st1..st4 (contiguous)
    hipMemsetAsync(ws + 62291968, 0, 273920, stream);

    // fused render + weight transforms
    prep_kernel<<<5144, 256, 0, stream>>>(input_data, rendered, w1, w2, w3, wT1, wT2, wT3);

    // conv1: [65536,480]x[480,64] — 256 blocks x 4 waves, NT=4, CH=5, fused stats
    conv_mfma<16, 64, 68, 10, 5, 3, 1, 4, 5, 4><<<256, 256, 0, stream>>>(rendered, wT1, conv1out, st1);
    bnpad_kernel<<<20736, 256, 0, stream>>>(conv1out, st1, g1, b1, pad1, 6, 32, 36,
                                            1.f / 65536.f, 5308416);

    // conv2: [16384,1600]x[1600,128] — 256 blocks x 4 waves, NCO=4, NT=2, CH=10 (R5)
    conv_mfma<64, 128, 36, 8, 4, 10, 4, 2, 10, 4><<<256, 256, 0, stream>>>(pad1, wT2, conv2out, st2);
    bnpad_kernel<<<12800, 256, 0, stream>>>(conv2out, st2, g2, b2, pad2, 7, 16, 20,
                                            1.f / 16384.f, 3276800);

    // conv3: [4096,3200]x[3200,256] — KS=2: 2x32x8 = 512 blocks x 2 waves, CH=10
    conv_split<128, 256, 20, 6, 3, 20, 32, 8, 2, 10, 2, 2><<<512, 128, 0, stream>>>(pad2, wT3, conv3parts);
    stats_part<<<512, 256, 0, stream>>>(conv3parts, st3, 256, 4096, 32, 2, 2, 1048576);
    bn_nchw_kernel<<<4096, 256, 0, stream>>>(conv3parts, st3, g3, b3, a4, 1048576, 2, 1048576);

    // conv4: [64,16384] x [1024,16384]^T -> [64,1024], split-K=16 (atomic h4)
    conv4_mfma<<<256, 256, 0, stream>>>(a4, w4, h4);
    stats_part<<<16, 256, 0, stream>>>(h4, st4, 1024, 64, 64, 4, 1, 0);

    // conv5 (inline BN4)
    conv5_kernel<<<64, 256, 0, stream>>>(h4, st4, g4, b4, w5, b5, (float*)d_out);
}